// Round 3
// baseline (326.970 us; speedup 1.0000x reference)
//
#include <hip/hip_runtime.h>

#define N_NODES 50000
#define N_REL 16
#define N_BASIS 8
#define N_EDGES 800000
#define CAP 64              // bucket capacity; deg ~ Poisson(16), P(>64) ~ 1e-19

#define WREL_BLOCKS 340     // (17*4096 + 17*1024)/256
#define ZERO_BLOCKS 49      // ceil(12504 int4 / 256)
#define XBF_BLOCKS 1563     // ceil(400000 / 256)  (50000*64 / 8 per thread)
#define SC_BLOCKS 3125      // 800000 / 256
#define AGG_BLOCKS 3125     // 50000 / 16 exact -> no pad nodes anywhere

typedef short s8v __attribute__((ext_vector_type(8)));    // 8 bf16 MFMA A/B frag
typedef float f4v __attribute__((ext_vector_type(4)));    // 4 fp32 MFMA C/D frag

__device__ inline unsigned short f2bf(float f) {
    union { float f; unsigned u; } v; v.f = f;
    unsigned r = (v.u + 0x7FFFu + ((v.u >> 16) & 1u)) >> 16;   // RNE
    return (unsigned short)r;
}

// a[0..3] += 4 bf16 packed in int2
__device__ __forceinline__ void acc4(float* a, int2 p) {
    a[0] += __int_as_float((int)((unsigned)p.x << 16));
    a[1] += __int_as_float(p.x & (int)0xFFFF0000u);
    a[2] += __int_as_float((int)((unsigned)p.y << 16));
    a[3] += __int_as_float(p.y & (int)0xFFFF0000u);
}

// ---- pre-pass: wrel weights || cursor zero || x -> bf16 cast ----
__global__ __launch_bounds__(256) void k_pre(const float* __restrict__ x,
                                             const float* __restrict__ b1, const float* __restrict__ c1,
                                             const float* __restrict__ s1f,
                                             const float* __restrict__ b2, const float* __restrict__ c2,
                                             const float* __restrict__ s2f,
                                             unsigned short* __restrict__ w1T,
                                             unsigned short* __restrict__ w2T,
                                             unsigned short* __restrict__ xbf,
                                             int* __restrict__ cursor) {
    int bid = blockIdx.x;
    if (bid >= WREL_BLOCKS + ZERO_BLOCKS) {
        int i = (bid - WREL_BLOCKS - ZERO_BLOCKS) * 256 + threadIdx.x;
        if (i < 400000) {
            const float4* xs = (const float4*)x + (size_t)i * 2;
            float4 v0 = xs[0], v1 = xs[1];
            int4 w;
            w.x = (int)(((unsigned)f2bf(v0.y) << 16) | f2bf(v0.x));
            w.y = (int)(((unsigned)f2bf(v0.w) << 16) | f2bf(v0.z));
            w.z = (int)(((unsigned)f2bf(v1.y) << 16) | f2bf(v1.x));
            w.w = (int)(((unsigned)f2bf(v1.w) << 16) | f2bf(v1.z));
            *(int4*)(xbf + (size_t)i * 8) = w;
        }
        return;
    }
    if (bid >= WREL_BLOCKS) {
        int i = (bid - WREL_BLOCKS) * 256 + threadIdx.x;
        if (i < 12504) ((int4*)cursor)[i] = make_int4(0, 0, 0, 0);
        return;
    }
    int idx = bid * 256 + threadIdx.x;
    if (idx < 17 * 4096) {
        int r = idx >> 12, o = (idx >> 6) & 63, k = idx & 63;
        float acc = 0.f;
        if (r < 16) {
            #pragma unroll
            for (int b = 0; b < N_BASIS; b++) acc += c1[r * N_BASIS + b] * b1[b * 4096 + k * 64 + o];
        } else {
            acc = s1f[k * 64 + o];
        }
        w1T[idx] = f2bf(acc);
    } else {
        int idx2 = idx - 17 * 4096;
        if (idx2 < 17 * 1024) {
            int r = idx2 >> 10, o = (idx2 >> 6) & 15, k = idx2 & 63;
            float acc = 0.f;
            if (r < 16) {
                #pragma unroll
                for (int b = 0; b < N_BASIS; b++) acc += c2[r * N_BASIS + b] * b2[b * 1024 + k * 16 + o];
            } else {
                acc = s2f[k * 16 + o];
            }
            w2T[idx2] = f2bf(acc);
        }
    }
}

// ---- bucket scatter (R0-proven body) ----
__global__ __launch_bounds__(256) void k_scatter(const int* __restrict__ ei,
                                                 const int* __restrict__ et,
                                                 int* __restrict__ cursor,
                                                 int* __restrict__ sed) {
    int e = blockIdx.x * 256 + threadIdx.x;
    if (e < N_EDGES) {
        int src = ei[e];
        int dst = ei[N_EDGES + e];
        int t = et[e];
        int pos = atomicAdd(&cursor[dst], 1);
        if (pos < CAP) sed[dst * CAP + pos] = (t << 16) | src;
    }
}

// ---- phase 1 prologue: bucket load + per-rel histogram + counting sort.
//      BARRIER-HARDENED (R3): every cross-lane LDS dependency crosses a __syncthreads().
//      No reliance on wave-internal write->read ordering. ----
#define AGG_PROLOGUE()                                                      \
    int tid = threadIdx.x;                                                  \
    int j = tid >> 4, sub = tid & 15;                                       \
    int nb = blockIdx.x * 16;                                               \
    int n = nb + j;                                                         \
    int deg = cursor[n];                                                    \
    deg = deg < CAP ? deg : CAP;                                            \
    const int* bucket = sed + n * CAP;                                      \
    hist[j][sub] = 0;                                                       \
    __syncthreads();                                                        \
    for (int i = sub; i < deg; i += 16) {                                   \
        int e = bucket[i];                                                  \
        ebr[j][i] = e;                                                      \
        atomicAdd(&hist[j][e >> 16], 1);                                    \
    }                                                                       \
    __syncthreads();                                                        \
    {                                                                       \
        int st = 0;                                                         \
        _Pragma("unroll")                                                   \
        for (int t = 0; t < 16; t++) { int hv = hist[j][t]; if (t < sub) st += hv; } \
        sta[j][sub] = st;                                                   \
        cur[j][sub] = st;                                                   \
    }                                                                       \
    __syncthreads();                                                        \
    for (int i = sub; i < deg; i += 16) {                                   \
        int e = ebr[j][i];                                                  \
        int p = atomicAdd(&cur[j][e >> 16], 1);                             \
        ssrc[j][p] = e & 0xFFFF;                                            \
    }                                                                       \
    __syncthreads();

// ---- phase 2 gather: all 16 relations for this j-group's node into agg LDS.
//      Reads hist/sta/ssrc strictly after the prologue's final barrier. ----
#define GATHER_ALL(SRCMAT)                                                  \
    for (int r = 0; r < 16; r++) {                                          \
        int cnt = hist[j][r];                                               \
        int s0 = sta[j][r];                                                 \
        float a[4] = {0.f, 0.f, 0.f, 0.f};                                  \
        int i = 0;                                                          \
        for (; i + 2 <= cnt; i += 2) {                                      \
            int sA = ssrc[j][s0 + i];                                       \
            int sB = ssrc[j][s0 + i + 1];                                   \
            int2 pA = *(const int2*)(SRCMAT + sA * 64 + sub * 4);           \
            int2 pB = *(const int2*)(SRCMAT + sB * 64 + sub * 4);           \
            acc4(a, pA);                                                    \
            acc4(a, pB);                                                    \
        }                                                                   \
        if (i < cnt) {                                                      \
            int sA = ssrc[j][s0 + i];                                       \
            int2 pA = *(const int2*)(SRCMAT + sA * 64 + sub * 4);           \
            acc4(a, pA);                                                    \
        }                                                                   \
        float iv = 1.0f / (float)(cnt > 0 ? cnt : 1);                       \
        ushort4 o;                                                          \
        o.x = f2bf(a[0] * iv); o.y = f2bf(a[1] * iv);                       \
        o.z = f2bf(a[2] * iv); o.w = f2bf(a[3] * iv);                       \
        *(ushort4*)&agg[r][j][sub * 4] = o;                                 \
    }                                                                       \
    __syncthreads();

// ---- layer 1: aggregate xbf per relation -> MFMA sweep
//      Sum_r agg_r@W1_r + x@self1, relu -> h (bf16).
//      16 nodes/block, 256 thr; wave wv owns out-dims [wv*16, wv*16+16). ----
__global__ __launch_bounds__(256) void k_agg1(const int* __restrict__ cursor,
                                              const int* __restrict__ sed,
                                              const unsigned short* __restrict__ xbf,
                                              const unsigned short* __restrict__ w1T,
                                              unsigned short* __restrict__ h) {
    __shared__ int ebr[16][64];
    __shared__ int ssrc[16][64];
    __shared__ int hist[16][16];
    __shared__ int cur[16][16];
    __shared__ int sta[16][16];
    __shared__ __align__(16) unsigned short agg[16][16][72];   // stride 72: proven htile banks

    AGG_PROLOGUE();
    GATHER_ALL(xbf);

    int wv = tid >> 6, lane = tid & 63;
    int m = lane & 15, q = lane >> 4;
    int nn = nb + m;                                   // < 50000 always (3125*16 exact)
    const unsigned short* wpA = w1T + (wv * 16 + m) * 64 + q * 8;   // A[o=wv*16+m][k]
    f4v D = (f4v){0.f, 0.f, 0.f, 0.f};
    #pragma unroll 4
    for (int r = 0; r < 16; r++) {
        s8v A0 = *(const s8v*)(wpA + r * 4096);
        s8v A1 = *(const s8v*)(wpA + r * 4096 + 32);
        s8v B0 = *(const s8v*)&agg[r][m][q * 8];
        s8v B1 = *(const s8v*)&agg[r][m][32 + q * 8];
        D = __builtin_amdgcn_mfma_f32_16x16x32_bf16(A0, B0, D, 0, 0, 0);
        D = __builtin_amdgcn_mfma_f32_16x16x32_bf16(A1, B1, D, 0, 0, 0);
    }
    {   // self term: relation slot 16, B straight from xbf
        s8v A0 = *(const s8v*)(wpA + 16 * 4096);
        s8v A1 = *(const s8v*)(wpA + 16 * 4096 + 32);
        s8v B0 = *(const s8v*)(xbf + (size_t)nn * 64 + q * 8);
        s8v B1 = *(const s8v*)(xbf + (size_t)nn * 64 + 32 + q * 8);
        D = __builtin_amdgcn_mfma_f32_16x16x32_bf16(A0, B0, D, 0, 0, 0);
        D = __builtin_amdgcn_mfma_f32_16x16x32_bf16(A1, B1, D, 0, 0, 0);
    }
    ushort4 o;
    o.x = f2bf(D[0] > 0.f ? D[0] : 0.f);
    o.y = f2bf(D[1] > 0.f ? D[1] : 0.f);
    o.z = f2bf(D[2] > 0.f ? D[2] : 0.f);
    o.w = f2bf(D[3] > 0.f ? D[3] : 0.f);
    *(ushort4*)(h + (size_t)nn * 64 + wv * 16 + q * 4) = o;    // D col=m(node), row=q*4+i(dim)
}

// ---- layer 2: aggregate h per relation -> MFMA sweep (wave 0),
//      Sum_r agg_r@W2_r + h@self2 -> out (fp32, 16-wide). ----
__global__ __launch_bounds__(256) void k_agg2(const int* __restrict__ cursor,
                                              const int* __restrict__ sed,
                                              const unsigned short* __restrict__ h,
                                              const unsigned short* __restrict__ w2T,
                                              float* __restrict__ out) {
    __shared__ int ebr[16][64];
    __shared__ int ssrc[16][64];
    __shared__ int hist[16][16];
    __shared__ int cur[16][16];
    __shared__ int sta[16][16];
    __shared__ __align__(16) unsigned short agg[16][16][72];

    AGG_PROLOGUE();
    GATHER_ALL(h);

    int wv = tid >> 6, lane = tid & 63;
    if (wv != 0) return;                               // no barriers past this point
    int m = lane & 15, q = lane >> 4;
    int nn = nb + m;
    const unsigned short* wpA = w2T + m * 64 + q * 8;  // A[o=m][k], 16 rows
    f4v D = (f4v){0.f, 0.f, 0.f, 0.f};
    #pragma unroll 4
    for (int r = 0; r < 16; r++) {
        s8v A0 = *(const s8v*)(wpA + r * 1024);
        s8v A1 = *(const s8v*)(wpA + r * 1024 + 32);
        s8v B0 = *(const s8v*)&agg[r][m][q * 8];
        s8v B1 = *(const s8v*)&agg[r][m][32 + q * 8];
        D = __builtin_amdgcn_mfma_f32_16x16x32_bf16(A0, B0, D, 0, 0, 0);
        D = __builtin_amdgcn_mfma_f32_16x16x32_bf16(A1, B1, D, 0, 0, 0);
    }
    {   // self term on h
        s8v A0 = *(const s8v*)(wpA + 16 * 1024);
        s8v A1 = *(const s8v*)(wpA + 16 * 1024 + 32);
        s8v B0 = *(const s8v*)(h + (size_t)nn * 64 + q * 8);
        s8v B1 = *(const s8v*)(h + (size_t)nn * 64 + 32 + q * 8);
        D = __builtin_amdgcn_mfma_f32_16x16x32_bf16(A0, B0, D, 0, 0, 0);
        D = __builtin_amdgcn_mfma_f32_16x16x32_bf16(A1, B1, D, 0, 0, 0);
    }
    *(float4*)(out + (size_t)nn * 16 + q * 4) = make_float4(D[0], D[1], D[2], D[3]);
}

extern "C" void kernel_launch(void* const* d_in, const int* in_sizes, int n_in,
                              void* d_out, int out_size, void* d_ws, size_t ws_size,
                              hipStream_t stream) {
    const float* x      = (const float*)d_in[0];
    const float* bases1 = (const float*)d_in[1];
    const float* coeffs1= (const float*)d_in[2];
    const float* self1  = (const float*)d_in[3];
    const float* bases2 = (const float*)d_in[4];
    const float* coeffs2= (const float*)d_in[5];
    const float* self2  = (const float*)d_in[6];
    const int*   ei     = (const int*)d_in[7];
    const int*   et     = (const int*)d_in[8];
    float* out = (float*)d_out;

    char* ws = (char*)d_ws;
    int*            cursor = (int*)(ws + 0);                    //    200,064 (50,016 ints, zeroed)
    unsigned short* w1T    = (unsigned short*)(ws + 200064);    //    139,264
    unsigned short* w2T    = (unsigned short*)(ws + 339328);    //     34,816
    int*            sed    = (int*)(ws + 374144);               // 12,800,000 (50000 x 64 x 4B)
    unsigned short* xbf    = (unsigned short*)(ws + 13174144);  //  6,400,000 (50,000 rows x 128B)
    unsigned short* h      = (unsigned short*)(ws + 19574144);  //  6,400,000 -> 25,974,144

    k_pre<<<WREL_BLOCKS + ZERO_BLOCKS + XBF_BLOCKS, 256, 0, stream>>>(
        x, bases1, coeffs1, self1, bases2, coeffs2, self2, w1T, w2T, xbf, cursor);
    k_scatter<<<SC_BLOCKS, 256, 0, stream>>>(ei, et, cursor, sed);
    k_agg1<<<AGG_BLOCKS, 256, 0, stream>>>(cursor, sed, xbf, w1T, h);
    k_agg2<<<AGG_BLOCKS, 256, 0, stream>>>(cursor, sed, h, w2T, out);
}

// Round 4
// 240.150 us; speedup vs baseline: 1.3615x; 1.3615x over previous
//
#include <hip/hip_runtime.h>

#define N_NODES 50000
#define N_REL 16
#define N_BASIS 8
#define N_EDGES 800000
#define CAP 64              // bucket capacity; deg ~ Poisson(16), P(>64) ~ 1e-19

#define WREL_BLOCKS 340     // (17*4096 + 17*1024)/256
#define ZERO_BLOCKS 49      // ceil(12504 int4 / 256)
#define XBF_BLOCKS 1563     // ceil(400000 / 256)  (50000*64 / 8 per thread)
#define SC_BLOCKS 3125      // 800000 / 256
#define AGG_BLOCKS 3125     // 50000 / 16 exact -> no pad nodes anywhere

typedef short s8v __attribute__((ext_vector_type(8)));    // 8 bf16 MFMA A/B frag
typedef float f4v __attribute__((ext_vector_type(4)));    // 4 fp32 MFMA C/D frag

__device__ inline unsigned short f2bf(float f) {
    union { float f; unsigned u; } v; v.f = f;
    unsigned r = (v.u + 0x7FFFu + ((v.u >> 16) & 1u)) >> 16;   // RNE
    return (unsigned short)r;
}
__device__ __forceinline__ float bfLO(int w) { return __int_as_float((int)((unsigned)w << 16)); }
__device__ __forceinline__ float bfHI(int w) { return __int_as_float(w & (int)0xFFFF0000u); }

// ---- pre-pass: wrel weights || cursor zero || x -> bf16 cast (R3-verified) ----
__global__ __launch_bounds__(256) void k_pre(const float* __restrict__ x,
                                             const float* __restrict__ b1, const float* __restrict__ c1,
                                             const float* __restrict__ s1f,
                                             const float* __restrict__ b2, const float* __restrict__ c2,
                                             const float* __restrict__ s2f,
                                             unsigned short* __restrict__ w1T,
                                             unsigned short* __restrict__ w2T,
                                             unsigned short* __restrict__ xbf,
                                             int* __restrict__ cursor) {
    int bid = blockIdx.x;
    if (bid >= WREL_BLOCKS + ZERO_BLOCKS) {
        int i = (bid - WREL_BLOCKS - ZERO_BLOCKS) * 256 + threadIdx.x;
        if (i < 400000) {
            const float4* xs = (const float4*)x + (size_t)i * 2;
            float4 v0 = xs[0], v1 = xs[1];
            int4 w;
            w.x = (int)(((unsigned)f2bf(v0.y) << 16) | f2bf(v0.x));
            w.y = (int)(((unsigned)f2bf(v0.w) << 16) | f2bf(v0.z));
            w.z = (int)(((unsigned)f2bf(v1.y) << 16) | f2bf(v1.x));
            w.w = (int)(((unsigned)f2bf(v1.w) << 16) | f2bf(v1.z));
            *(int4*)(xbf + (size_t)i * 8) = w;
        }
        return;
    }
    if (bid >= WREL_BLOCKS) {
        int i = (bid - WREL_BLOCKS) * 256 + threadIdx.x;
        if (i < 12504) ((int4*)cursor)[i] = make_int4(0, 0, 0, 0);
        return;
    }
    int idx = bid * 256 + threadIdx.x;
    if (idx < 17 * 4096) {
        int r = idx >> 12, o = (idx >> 6) & 63, k = idx & 63;
        float acc = 0.f;
        if (r < 16) {
            #pragma unroll
            for (int b = 0; b < N_BASIS; b++) acc += c1[r * N_BASIS + b] * b1[b * 4096 + k * 64 + o];
        } else {
            acc = s1f[k * 64 + o];
        }
        w1T[idx] = f2bf(acc);
    } else {
        int idx2 = idx - 17 * 4096;
        if (idx2 < 17 * 1024) {
            int r = idx2 >> 10, o = (idx2 >> 6) & 15, k = idx2 & 63;
            float acc = 0.f;
            if (r < 16) {
                #pragma unroll
                for (int b = 0; b < N_BASIS; b++) acc += c2[r * N_BASIS + b] * b2[b * 1024 + k * 16 + o];
            } else {
                acc = s2f[k * 16 + o];
            }
            w2T[idx2] = f2bf(acc);
        }
    }
}

// ---- bucket scatter (R0-proven body) ----
__global__ __launch_bounds__(256) void k_scatter(const int* __restrict__ ei,
                                                 const int* __restrict__ et,
                                                 int* __restrict__ cursor,
                                                 int* __restrict__ sed) {
    int e = blockIdx.x * 256 + threadIdx.x;
    if (e < N_EDGES) {
        int src = ei[e];
        int dst = ei[N_EDGES + e];
        int t = et[e];
        int pos = atomicAdd(&cursor[dst], 1);
        if (pos < CAP) sed[dst * CAP + pos] = (t << 16) | src;
    }
}

// ---- shared LDS layout for both agg kernels: 25,600 B -> 4 blocks/CU ----
struct AggLds {
    int esrt[16][64];                                          // sorted packed (r<<16|src)
    int hist[16][16];
    int cur[16][16];
    int sta[16][16];
    __align__(16) unsigned short agg[2][4][16][72];            // dbuf x 4-rel x node x dim (stride-72 banks)
};

// ---- prologue: bucket -> regs, histogram, prefix, counting sort into esrt.
//      R3-proven barrier discipline: every cross-lane LDS dep crosses __syncthreads. ----
__device__ __forceinline__ void agg_prologue(AggLds& S, const int* __restrict__ cursor,
                                             const int* __restrict__ sed,
                                             int j, int sub, int n, int& deg) {
    deg = cursor[n];
    deg = deg < CAP ? deg : CAP;
    const int* bucket = sed + n * CAP;
    int be0 = (sub      < deg) ? bucket[sub]      : -1;
    int be1 = (sub + 16 < deg) ? bucket[sub + 16] : -1;
    int be2 = (sub + 32 < deg) ? bucket[sub + 32] : -1;
    int be3 = (sub + 48 < deg) ? bucket[sub + 48] : -1;
    S.hist[j][sub] = 0;
    __syncthreads();
    if (be0 >= 0) atomicAdd(&S.hist[j][be0 >> 16], 1);
    if (be1 >= 0) atomicAdd(&S.hist[j][be1 >> 16], 1);
    if (be2 >= 0) atomicAdd(&S.hist[j][be2 >> 16], 1);
    if (be3 >= 0) atomicAdd(&S.hist[j][be3 >> 16], 1);
    __syncthreads();
    {
        int st = 0;
        #pragma unroll
        for (int t = 0; t < 16; t++) { int hv = S.hist[j][t]; if (t < sub) st += hv; }
        S.sta[j][sub] = st;
        S.cur[j][sub] = st;
    }
    __syncthreads();
    if (be0 >= 0) { int p = atomicAdd(&S.cur[j][be0 >> 16], 1); S.esrt[j][p] = be0; }
    if (be1 >= 0) { int p = atomicAdd(&S.cur[j][be1 >> 16], 1); S.esrt[j][p] = be1; }
    if (be2 >= 0) { int p = atomicAdd(&S.cur[j][be2 >> 16], 1); S.esrt[j][p] = be2; }
    if (be3 >= 0) { int p = atomicAdd(&S.cur[j][be3 >> 16], 1); S.esrt[j][p] = be3; }
    __syncthreads();
}

// ---- one walk phase: edges [start,end) cover relations [rbase, rbase+4) exactly
//      (phase boundaries sit on relation-run starts). Flush-on-boundary accumulate,
//      4 independent gather loads in flight per batch. ----
__device__ __forceinline__ void walk_phase(AggLds& S, const unsigned short* __restrict__ srcmat,
                                           int j, int sub, int start, int end, int rbase, int buf) {
    ushort4 z; z.x = 0; z.y = 0; z.z = 0; z.w = 0;
    #pragma unroll
    for (int rl = 0; rl < 4; rl++) *(ushort4*)&S.agg[buf][rl][j][sub * 4] = z;

    float a0 = 0.f, a1 = 0.f, a2 = 0.f, a3 = 0.f;
    int rprev = -1;
    auto flush = [&](int r) {
        float iv = 1.0f / (float)S.hist[j][r];
        ushort4 o;
        o.x = f2bf(a0 * iv); o.y = f2bf(a1 * iv); o.z = f2bf(a2 * iv); o.w = f2bf(a3 * iv);
        *(ushort4*)&S.agg[buf][r - rbase][j][sub * 4] = o;
    };
    auto proc = [&](int e, int2 p) {
        int r = e >> 16;
        if (r != rprev) {
            if (rprev >= 0) flush(rprev);
            a0 = a1 = a2 = a3 = 0.f;
            rprev = r;
        }
        a0 += bfLO(p.x); a1 += bfHI(p.x); a2 += bfLO(p.y); a3 += bfHI(p.y);
    };
    for (int ib = start; ib < end; ib += 4) {
        int rem = end - ib;
        int e0, e1 = 0, e2 = 0, e3 = 0;
        int2 p0, p1 = make_int2(0, 0), p2 = make_int2(0, 0), p3 = make_int2(0, 0);
        e0 = S.esrt[j][ib];
        p0 = *(const int2*)(srcmat + (e0 & 0xFFFF) * 64 + sub * 4);
        if (rem > 1) { e1 = S.esrt[j][ib + 1]; p1 = *(const int2*)(srcmat + (e1 & 0xFFFF) * 64 + sub * 4); }
        if (rem > 2) { e2 = S.esrt[j][ib + 2]; p2 = *(const int2*)(srcmat + (e2 & 0xFFFF) * 64 + sub * 4); }
        if (rem > 3) { e3 = S.esrt[j][ib + 3]; p3 = *(const int2*)(srcmat + (e3 & 0xFFFF) * 64 + sub * 4); }
        proc(e0, p0);
        if (rem > 1) proc(e1, p1);
        if (rem > 2) proc(e2, p2);
        if (rem > 3) proc(e3, p3);
    }
    if (rprev >= 0) flush(rprev);
}

// ---- MFMA consume of one 4-relation buffer (R3-proven fragment mappings) ----
__device__ __forceinline__ void mfma4(AggLds& S, const unsigned short* __restrict__ wpA,
                                      int rbase, int buf, int m, int q, int wstride, f4v& D) {
    #pragma unroll
    for (int rl = 0; rl < 4; rl++) {
        int r = rbase + rl;
        s8v A0 = *(const s8v*)(wpA + r * wstride);
        s8v A1 = *(const s8v*)(wpA + r * wstride + 32);
        s8v B0 = *(const s8v*)&S.agg[buf][rl][m][q * 8];
        s8v B1 = *(const s8v*)&S.agg[buf][rl][m][32 + q * 8];
        D = __builtin_amdgcn_mfma_f32_16x16x32_bf16(A0, B0, D, 0, 0, 0);
        D = __builtin_amdgcn_mfma_f32_16x16x32_bf16(A1, B1, D, 0, 0, 0);
    }
}

// ---- layer 1: phased gather||MFMA, Sum_r agg_r@W1_r + x@self1, relu -> h (bf16) ----
__global__ __launch_bounds__(256) void k_agg1(const int* __restrict__ cursor,
                                              const int* __restrict__ sed,
                                              const unsigned short* __restrict__ xbf,
                                              const unsigned short* __restrict__ w1T,
                                              unsigned short* __restrict__ h) {
    __shared__ AggLds S;
    int tid = threadIdx.x;
    int j = tid >> 4, sub = tid & 15;
    int nb = blockIdx.x * 16;
    int n = nb + j;
    int deg;
    agg_prologue(S, cursor, sed, j, sub, n, deg);

    int b1p = S.sta[j][4], b2p = S.sta[j][8], b3p = S.sta[j][12];
    int wv = tid >> 6, lane = tid & 63;
    int m = lane & 15, q = lane >> 4;
    int nn = nb + m;
    const unsigned short* wpA = w1T + (wv * 16 + m) * 64 + q * 8;   // A[o=wv*16+m][k]
    f4v D = (f4v){0.f, 0.f, 0.f, 0.f};

    walk_phase(S, xbf, j, sub, 0,   b1p, 0,  0);                 // region 0: write buf0
    __syncthreads();
    walk_phase(S, xbf, j, sub, b1p, b2p, 4,  1);                 // region 1: write buf1
    mfma4(S, wpA, 0, 0, m, q, 4096, D);                          //           read  buf0
    __syncthreads();
    walk_phase(S, xbf, j, sub, b2p, b3p, 8,  0);                 // region 2: write buf0
    mfma4(S, wpA, 4, 1, m, q, 4096, D);                          //           read  buf1
    __syncthreads();
    walk_phase(S, xbf, j, sub, b3p, deg, 12, 1);                 // region 3: write buf1
    mfma4(S, wpA, 8, 0, m, q, 4096, D);                          //           read  buf0
    __syncthreads();
    mfma4(S, wpA, 12, 1, m, q, 4096, D);                         // region 4: read buf1

    {   // self term: relation slot 16, B straight from xbf
        s8v A0 = *(const s8v*)(wpA + 16 * 4096);
        s8v A1 = *(const s8v*)(wpA + 16 * 4096 + 32);
        s8v B0 = *(const s8v*)(xbf + (size_t)nn * 64 + q * 8);
        s8v B1 = *(const s8v*)(xbf + (size_t)nn * 64 + 32 + q * 8);
        D = __builtin_amdgcn_mfma_f32_16x16x32_bf16(A0, B0, D, 0, 0, 0);
        D = __builtin_amdgcn_mfma_f32_16x16x32_bf16(A1, B1, D, 0, 0, 0);
    }
    ushort4 o;
    o.x = f2bf(D[0] > 0.f ? D[0] : 0.f);
    o.y = f2bf(D[1] > 0.f ? D[1] : 0.f);
    o.z = f2bf(D[2] > 0.f ? D[2] : 0.f);
    o.w = f2bf(D[3] > 0.f ? D[3] : 0.f);
    *(ushort4*)(h + (size_t)nn * 64 + wv * 16 + q * 4) = o;      // D col=m(node), row=q*4+i(dim)
}

// ---- layer 2: same skeleton on h; MFMA consume on wave 0 only (out is 16-wide) ----
__global__ __launch_bounds__(256) void k_agg2(const int* __restrict__ cursor,
                                              const int* __restrict__ sed,
                                              const unsigned short* __restrict__ h,
                                              const unsigned short* __restrict__ w2T,
                                              float* __restrict__ out) {
    __shared__ AggLds S;
    int tid = threadIdx.x;
    int j = tid >> 4, sub = tid & 15;
    int nb = blockIdx.x * 16;
    int n = nb + j;
    int deg;
    agg_prologue(S, cursor, sed, j, sub, n, deg);

    int b1p = S.sta[j][4], b2p = S.sta[j][8], b3p = S.sta[j][12];
    int wv = tid >> 6, lane = tid & 63;
    int m = lane & 15, q = lane >> 4;
    int nn = nb + m;
    const unsigned short* wpA = w2T + m * 64 + q * 8;            // A[o=m][k], 16 rows
    f4v D = (f4v){0.f, 0.f, 0.f, 0.f};

    walk_phase(S, h, j, sub, 0,   b1p, 0,  0);
    __syncthreads();
    walk_phase(S, h, j, sub, b1p, b2p, 4,  1);
    if (wv == 0) mfma4(S, wpA, 0, 0, m, q, 1024, D);
    __syncthreads();
    walk_phase(S, h, j, sub, b2p, b3p, 8,  0);
    if (wv == 0) mfma4(S, wpA, 4, 1, m, q, 1024, D);
    __syncthreads();
    walk_phase(S, h, j, sub, b3p, deg, 12, 1);
    if (wv == 0) mfma4(S, wpA, 8, 0, m, q, 1024, D);
    __syncthreads();
    if (wv == 0) {
        mfma4(S, wpA, 12, 1, m, q, 1024, D);
        // self term on h
        s8v A0 = *(const s8v*)(wpA + 16 * 1024);
        s8v A1 = *(const s8v*)(wpA + 16 * 1024 + 32);
        s8v B0 = *(const s8v*)(h + (size_t)nn * 64 + q * 8);
        s8v B1 = *(const s8v*)(h + (size_t)nn * 64 + 32 + q * 8);
        D = __builtin_amdgcn_mfma_f32_16x16x32_bf16(A0, B0, D, 0, 0, 0);
        D = __builtin_amdgcn_mfma_f32_16x16x32_bf16(A1, B1, D, 0, 0, 0);
        *(float4*)(out + (size_t)nn * 16 + q * 4) = make_float4(D[0], D[1], D[2], D[3]);
    }
}

extern "C" void kernel_launch(void* const* d_in, const int* in_sizes, int n_in,
                              void* d_out, int out_size, void* d_ws, size_t ws_size,
                              hipStream_t stream) {
    const float* x      = (const float*)d_in[0];
    const float* bases1 = (const float*)d_in[1];
    const float* coeffs1= (const float*)d_in[2];
    const float* self1  = (const float*)d_in[3];
    const float* bases2 = (const float*)d_in[4];
    const float* coeffs2= (const float*)d_in[5];
    const float* self2  = (const float*)d_in[6];
    const int*   ei     = (const int*)d_in[7];
    const int*   et     = (const int*)d_in[8];
    float* out = (float*)d_out;

    char* ws = (char*)d_ws;
    int*            cursor = (int*)(ws + 0);                    //    200,064 (50,016 ints, zeroed)
    unsigned short* w1T    = (unsigned short*)(ws + 200064);    //    139,264
    unsigned short* w2T    = (unsigned short*)(ws + 339328);    //     34,816
    int*            sed    = (int*)(ws + 374144);               // 12,800,000 (50000 x 64 x 4B)
    unsigned short* xbf    = (unsigned short*)(ws + 13174144);  //  6,400,000 (50,000 rows x 128B)
    unsigned short* h      = (unsigned short*)(ws + 19574144);  //  6,400,000 -> 25,974,144

    k_pre<<<WREL_BLOCKS + ZERO_BLOCKS + XBF_BLOCKS, 256, 0, stream>>>(
        x, bases1, coeffs1, self1, bases2, coeffs2, self2, w1T, w2T, xbf, cursor);
    k_scatter<<<SC_BLOCKS, 256, 0, stream>>>(ei, et, cursor, sed);
    k_agg1<<<AGG_BLOCKS, 256, 0, stream>>>(cursor, sed, xbf, w1T, h);
    k_agg2<<<AGG_BLOCKS, 256, 0, stream>>>(cursor, sed, h, w2T, out);
}